// Round 10
// baseline (356.306 us; speedup 1.0000x reference)
//
#include <hip/hip_runtime.h>
#include <math.h>

typedef unsigned short u16;
typedef unsigned int u32;

#define B_ 4
#define N_ 2048
#define D_ 512
#define H_ 8
#define HD_ 64
#define MLP_H_ 2048
#define EPS_ 1e-5f
#define C2_ 14.426950408889634f          // 10/ln2
#define QSCALE_ 0.1803368801111204f     // 0.125/ln2
#define EL2_ 0.0014426950408889634f     // 1/(1000*ln2)

#if __has_builtin(__builtin_amdgcn_exp2f)
#define EXP2(x) __builtin_amdgcn_exp2f(x)
#else
#define EXP2(x) exp2f(x)
#endif
#if __has_builtin(__builtin_amdgcn_fmed3f)
#define CLAMP0C(x) __builtin_amdgcn_fmed3f((x), 0.0f, C2_)
#else
#define CLAMP0C(x) fminf(fmaxf((x), 0.0f), C2_)
#endif

// ---------- bf16 helpers ----------
__device__ __forceinline__ u16 bf16_rne(float x) {
  u32 u = __float_as_uint(x);
  u32 r = (u + 0x7FFFu + ((u >> 16) & 1u)) >> 16;
  return (u16)r;
}
#if __has_builtin(__builtin_amdgcn_cvt_pk_bf16_f32)
typedef __bf16 bf2_t __attribute__((ext_vector_type(2)));
__device__ __forceinline__ u32 pk_bf16(float a, float b) {
  bf2_t v = __builtin_amdgcn_cvt_pk_bf16_f32(a, b);
  u32 r; __builtin_memcpy(&r, &v, 4); return r;
}
#else
__device__ __forceinline__ u32 pk_bf16(float a, float b) {
  return (u32)bf16_rne(a) | ((u32)bf16_rne(b) << 16);
}
#endif
__device__ __forceinline__ void bf16_split(float x, u16& h, u16& l) {
  h = bf16_rne(x);
  float hf = __uint_as_float(((u32)h) << 16);
  l = bf16_rne(x - hf);
}

typedef __attribute__((ext_vector_type(8))) short bfrag;
typedef __attribute__((ext_vector_type(4))) float ffrag;

#define LDS_AS(p) ((__attribute__((address_space(3))) void*)(p))
#define GLB_AS(p) ((const __attribute__((address_space(1))) void*)(p))

// ---------------- LayerNorm -> bf16 out (optionally fuses elevation pre-scale) ----
__global__ __launch_bounds__(256) void ln_kernel(
    const float* __restrict__ x, const float* __restrict__ g,
    const float* __restrict__ b, u16* __restrict__ o,
    const float* __restrict__ elev, const float* __restrict__ alpha,
    float* __restrict__ e2)
{
  __shared__ float red[8];
  int row = blockIdx.x;
  int tid = threadIdx.x;
  if (e2 && tid == 0) e2[row] = elev[row] * (alpha[0] * EL2_);
  const float* xr = x + (size_t)row * D_;
  float v0 = xr[tid], v1 = xr[tid + 256];
  float s = v0 + v1;
  #pragma unroll
  for (int off = 32; off > 0; off >>= 1) s += __shfl_xor(s, off, 64);
  if ((tid & 63) == 0) red[tid >> 6] = s;
  __syncthreads();
  float mean = (red[0] + red[1] + red[2] + red[3]) * (1.0f / D_);
  float d0 = v0 - mean, d1 = v1 - mean;
  float vs = d0 * d0 + d1 * d1;
  #pragma unroll
  for (int off = 32; off > 0; off >>= 1) vs += __shfl_xor(vs, off, 64);
  if ((tid & 63) == 0) red[4 + (tid >> 6)] = vs;
  __syncthreads();
  float var = (red[4] + red[5] + red[6] + red[7]) * (1.0f / D_);
  float r = rsqrtf(var + EPS_);
  u16* orow = o + (size_t)row * D_;
  orow[tid]       = bf16_rne(d0 * r * g[tid] + b[tid]);
  orow[tid + 256] = bf16_rne(d1 * r * g[tid + 256] + b[tid + 256]);
}

// ---------------- fused weight split+transpose ----------------
__device__ __forceinline__ void wsplit_body(
    const float* __restrict__ W, u16* __restrict__ Thi, u16* __restrict__ Tlo,
    int K, int N, int bx, int by, int tid)
{
  __shared__ float tile[64][65];
  int n0 = bx * 64, k0 = by * 64;
  int c = tid & 63, r4 = tid >> 6;
  #pragma unroll
  for (int i = 0; i < 16; i++) {
    int r = r4 + i * 4;
    tile[r][c] = W[(size_t)(k0 + r) * N + n0 + c];
  }
  __syncthreads();
  #pragma unroll
  for (int i = 0; i < 16; i++) {
    int rn = r4 + i * 4;
    float v = tile[c][rn];
    size_t o = (size_t)(n0 + rn) * K + k0 + c;
    if (Tlo) {
      u16 h, l; bf16_split(v, h, l);
      Thi[o] = h; Tlo[o] = l;
    } else {
      Thi[o] = bf16_rne(v);
    }
  }
}

__global__ __launch_bounds__(256) void wsplit_all(
    const float* __restrict__ qkv_w, const float* __restrict__ proj_w,
    const float* __restrict__ fc1_w, const float* __restrict__ fc2_w,
    u16* __restrict__ qw_hi, u16* __restrict__ qw_lo,
    u16* __restrict__ pw_hi, u16* __restrict__ f1_hi, u16* __restrict__ f2_hi)
{
  int id = blockIdx.x;
  int tid = threadIdx.x;
  if (id < 192) {
    wsplit_body(qkv_w, qw_hi, qw_lo, 512, 1536, id % 24, id / 24, tid);
  } else if (id < 256) {
    int l = id - 192;
    wsplit_body(proj_w, pw_hi, nullptr, 512, 512, l % 8, l / 8, tid);
  } else if (id < 512) {
    int l = id - 256;
    wsplit_body(fc1_w, f1_hi, nullptr, 512, 2048, l % 32, l / 32, tid);
  } else {
    int l = id - 512;
    wsplit_body(fc2_w, f2_hi, nullptr, 2048, 512, l % 8, l / 8, tid);
  }
}

// ---------------- common staging: swizzled 32-k sub-tile ----------------
template<int ROWS>
__device__ __forceinline__ void stage32(const u16* __restrict__ src, int ld,
                                        int r0, int k0, u16* lds, int lane, int wave)
{
  #pragma unroll
  for (int i = 0; i < ROWS / 64; i++) {
    int seg = wave * (ROWS / 64) + i;
    int chunk = seg * 64 + lane;
    int r = chunk >> 2;
    int c = (chunk & 3) ^ ((r >> 1) & 3);
    const u16* g = src + (size_t)(r0 + r) * ld + k0 + c * 8;
    __builtin_amdgcn_global_load_lds(GLB_AS(g), LDS_AS((char*)lds + seg * 1024), 16, 0, 0);
  }
}

__device__ __forceinline__ int swz_off(int R, int quad) {
  return R * 32 + ((quad ^ ((R >> 1) & 3)) * 8);   // u16 units within a 32-k tile
}

// ---------------- fused QKV GEMM: C = A @ qkv_w, epilogue by column range ------
// 128x64 tile, waves 4x1. cols 0-511: Q (scale+split); 512-1023: K (hi); >=1024: V^T.
__global__ __launch_bounds__(256) void qkv_gemm(
    const u16* __restrict__ Ahi,
    const u16* __restrict__ Whi, const u16* __restrict__ Wlo,
    u16* __restrict__ qkh, u16* __restrict__ qkl, u16* __restrict__ vth)
{
  __shared__ __align__(16) u16 As0[128 * 32], As1[128 * 32];
  __shared__ __align__(16) u16 Bh0[64 * 32],  Bh1[64 * 32];
  __shared__ __align__(16) u16 Bl0[64 * 32],  Bl1[64 * 32];

  int tid = threadIdx.x;
  int lane = tid & 63, wave = tid >> 6;
  int ln = lane & 15, quad = lane >> 4;
  int m0 = blockIdx.y * 128, n0 = blockIdx.x * 64;
  bool lo = (n0 < 1024);   // Q/K columns use the 2-term weight path

  ffrag acc[2][4] = {};

  for (int k0 = 0; k0 < D_; k0 += 64) {
    stage32<128>(Ahi, D_, m0, k0,      As0, lane, wave);
    stage32<128>(Ahi, D_, m0, k0 + 32, As1, lane, wave);
    stage32<64>(Whi, D_, n0, k0,      Bh0, lane, wave);
    stage32<64>(Whi, D_, n0, k0 + 32, Bh1, lane, wave);
    if (lo) {
      stage32<64>(Wlo, D_, n0, k0,      Bl0, lane, wave);
      stage32<64>(Wlo, D_, n0, k0 + 32, Bl1, lane, wave);
    }
    __syncthreads();

    #pragma unroll
    for (int hf = 0; hf < 2; hf++) {
      const u16* Asf = hf ? As1 : As0;
      const u16* Bhf = hf ? Bh1 : Bh0;
      const u16* Blf = hf ? Bl1 : Bl0;
      bfrag ah[2], bh[4], bl[4];
      #pragma unroll
      for (int t = 0; t < 2; t++)
        ah[t] = *(const bfrag*)(Asf + swz_off(wave * 32 + t * 16 + ln, quad));
      #pragma unroll
      for (int u = 0; u < 4; u++) {
        int off = swz_off(u * 16 + ln, quad);
        bh[u] = *(const bfrag*)(Bhf + off);
        bl[u] = *(const bfrag*)(Blf + off);
      }
      #pragma unroll
      for (int ti = 0; ti < 2; ti++) {
        #pragma unroll
        for (int tj = 0; tj < 4; tj++) {
          acc[ti][tj] = __builtin_amdgcn_mfma_f32_16x16x32_bf16(ah[ti], bh[tj], acc[ti][tj], 0, 0, 0);
          if (lo)
            acc[ti][tj] = __builtin_amdgcn_mfma_f32_16x16x32_bf16(ah[ti], bl[tj], acc[ti][tj], 0, 0, 0);
        }
      }
    }
    __syncthreads();
  }

  #pragma unroll
  for (int tj = 0; tj < 4; tj++) {
    int col = n0 + tj * 16 + ln;
    #pragma unroll
    for (int ti = 0; ti < 2; ti++) {
      int rw = m0 + wave * 32 + ti * 16 + quad * 4;
      if (col < 512) {          // Q: scale + split
        #pragma unroll
        for (int r = 0; r < 4; r++) {
          float y = acc[ti][tj][r] * QSCALE_;
          u16 hh, ll; bf16_split(y, hh, ll);
          qkh[(size_t)(rw + r) * 1024 + col] = hh;
          qkl[(size_t)(rw + r) * 1024 + col] = ll;
        }
      } else if (col < 1024) {  // K: hi only
        #pragma unroll
        for (int r = 0; r < 4; r++)
          qkh[(size_t)(rw + r) * 1024 + col] = bf16_rne(acc[ti][tj][r]);
      } else {                  // V: write V^T [B,H,HD,N]
        int h = (col - 1024) >> 6, d = (col - 1024) & 63;
        int bb = rw >> 11, n = rw & (N_ - 1);
        u32 w0 = pk_bf16(acc[ti][tj][0], acc[ti][tj][1]);
        u32 w1 = pk_bf16(acc[ti][tj][2], acc[ti][tj][3]);
        size_t dst = ((size_t)((bb * H_ + h) * HD_ + d)) * N_ + n;
        *(uint2*)(vth + dst) = make_uint2(w0, w1);
      }
    }
  }
}

// ---------------- generic GEMM (proj / fc1 / fc2) ----------------
template<int TBM, int TBN, int WR, int WC>
__global__ __launch_bounds__(256) void gemm_tpl(
    const u16* __restrict__ Ahi, const u16* __restrict__ Whi,
    const float* __restrict__ bias, const float* __restrict__ res,
    float* __restrict__ Cf, u16* __restrict__ Ohi,
    int M, int K, int N, int act)
{
  constexpr int MF = TBM / (WR * 16);
  constexpr int NF = TBN / (WC * 16);
  constexpr int AT = TBM * 32;
  constexpr int BT = TBN * 32;
  __shared__ __align__(16) u16 smem[2 * AT + 2 * BT];
  u16* As0 = smem;          u16* As1 = smem + AT;
  u16* Bh0 = smem + 2 * AT; u16* Bh1 = smem + 2 * AT + BT;

  int tid = threadIdx.x;
  int lane = tid & 63, wave = tid >> 6;
  int wr = wave / WC, wc = wave % WC;
  int ln = lane & 15, quad = lane >> 4;
  int m0 = blockIdx.y * TBM, n0 = blockIdx.x * TBN;

  ffrag acc[MF][NF] = {};

  for (int k0 = 0; k0 < K; k0 += 64) {
    stage32<TBM>(Ahi, K, m0, k0,      As0, lane, wave);
    stage32<TBM>(Ahi, K, m0, k0 + 32, As1, lane, wave);
    stage32<TBN>(Whi, K, n0, k0,      Bh0, lane, wave);
    stage32<TBN>(Whi, K, n0, k0 + 32, Bh1, lane, wave);
    __syncthreads();

    #pragma unroll
    for (int hf = 0; hf < 2; hf++) {
      const u16* Asf = hf ? As1 : As0;
      const u16* Bhf = hf ? Bh1 : Bh0;
      bfrag ah[MF], bh[NF];
      #pragma unroll
      for (int t = 0; t < MF; t++)
        ah[t] = *(const bfrag*)(Asf + swz_off(wr * (TBM / WR) + t * 16 + ln, quad));
      #pragma unroll
      for (int u = 0; u < NF; u++)
        bh[u] = *(const bfrag*)(Bhf + swz_off(wc * (TBN / WC) + u * 16 + ln, quad));
      #pragma unroll
      for (int ti = 0; ti < MF; ti++)
        #pragma unroll
        for (int tj = 0; tj < NF; tj++)
          acc[ti][tj] = __builtin_amdgcn_mfma_f32_16x16x32_bf16(ah[ti], bh[tj], acc[ti][tj], 0, 0, 0);
    }
    __syncthreads();
  }

  #pragma unroll
  for (int tj = 0; tj < NF; tj++) {
    int col = n0 + wc * (TBN / WC) + tj * 16 + ln;
    float bv = bias ? bias[col] : 0.f;
    #pragma unroll
    for (int ti = 0; ti < MF; ti++) {
      int rw = m0 + wr * (TBM / WR) + ti * 16 + quad * 4;
      #pragma unroll
      for (int r = 0; r < 4; r++) {
        float y = acc[ti][tj][r] + bv;
        if (act) y = 0.5f * y * (1.f + erff(y * 0.70710678118654752f));
        if (res) y += res[(size_t)(rw + r) * N + col];
        if (Cf) Cf[(size_t)(rw + r) * N + col] = y;
        if (Ohi) Ohi[(size_t)(rw + r) * N + col] = bf16_rne(y);
      }
    }
  }
}

// ---------------- MFMA flash attention: double-buffered K/V, 1 barrier/iter ----
__device__ __forceinline__ void stage_tile64(const u16* __restrict__ gbase, size_t rstride,
                                             u16* lds, int wave, int lane)
{
  #pragma unroll
  for (int i = 0; i < 2; i++) {
    int seg = wave * 2 + i;
    int chunk = seg * 64 + lane;            // phys chunk 0..511
    int ch = chunk >> 8;                    // 32-elem half
    int pc = chunk & 255;
    int r = pc >> 2;
    int q = (pc & 3) ^ ((r >> 1) & 3);
    const u16* g = gbase + (size_t)r * rstride + ch * 32 + q * 8;
    __builtin_amdgcn_global_load_lds(GLB_AS(g), LDS_AS((char*)lds + seg * 1024), 16, 0, 0);
  }
}

__device__ __forceinline__ int frag_off(int c, int R, int quad) {
  return c * 2048 + R * 32 + ((quad ^ ((R >> 1) & 3)) * 8);   // u16 units
}

__global__ __launch_bounds__(256) void attn_mfma_kernel(
    const u16* __restrict__ qkh, const u16* __restrict__ qkl,
    const u16* __restrict__ vth,
    const float* __restrict__ e2, u16* __restrict__ outb)
{
  __shared__ __align__(16) u16 Kh[2][4096];
  __shared__ __align__(16) u16 Vh[2][4096];
  __shared__ __align__(16) u16 Pw[4][16][72];

  int b = blockIdx.z, h = blockIdx.y;
  int q0 = blockIdx.x * 64;
  int tid = threadIdx.x;
  int lane = tid & 63, wq = tid >> 6;
  int ln = lane & 15, quad = lane >> 4;

  // ---- stage Q: hi -> Kh[0], lo -> Vh[0] ----
  const u16* qb_h = qkh + ((size_t)(b * N_ + q0)) * 1024 + h * 64;
  const u16* qb_l = qkl + ((size_t)(b * N_ + q0)) * 1024 + h * 64;
  stage_tile64(qb_h, 1024, Kh[0], wq, lane);
  stage_tile64(qb_l, 1024, Vh[0], wq, lane);
  __syncthreads();

  bfrag qfh[2], qfl[2];
  #pragma unroll
  for (int c = 0; c < 2; c++) {
    int off = frag_off(c, wq * 16 + ln, quad);
    qfh[c] = *(const bfrag*)(Kh[0] + off);
    qfl[c] = *(const bfrag*)(Vh[0] + off);
  }
  __syncthreads();   // all waves done reading Q before tile-0 staging overwrites

  float e2q = e2[b * N_ + q0 + wq * 16 + ln];
  float m_i = -3.0e38f, l_i = 0.f;
  ffrag O[4] = {};

  const u16* kp = qkh + (size_t)b * N_ * 1024 + 512 + h * 64;
  const u16* vp = vth + (size_t)(b * H_ + h) * HD_ * N_;
  const float* ep = e2 + b * N_;

  // preload tile 0
  stage_tile64(kp, 1024, Kh[0], wq, lane);
  stage_tile64(vp, N_, Vh[0], wq, lane);
  kp += (size_t)64 * 1024;
  vp += 64;
  __syncthreads();

  for (int it = 0; it < N_ / 64; it++) {
    int cur = it & 1;
    if (it < N_ / 64 - 1) {        // stage next tile into the other buffer (async)
      stage_tile64(kp, 1024, Kh[cur ^ 1], wq, lane);
      stage_tile64(vp, N_, Vh[cur ^ 1], wq, lane);
      kp += (size_t)64 * 1024;
      vp += 64;
    }

    // ---- S^T = K (Qh+Ql)^T ----
    ffrag S[4];
    #pragma unroll
    for (int kt = 0; kt < 4; kt++) {
      ffrag s = {0.f, 0.f, 0.f, 0.f};
      #pragma unroll
      for (int c = 0; c < 2; c++) {
        bfrag kf = *(const bfrag*)(Kh[cur] + frag_off(c, kt * 16 + ln, quad));
        s = __builtin_amdgcn_mfma_f32_16x16x32_bf16(kf, qfh[c], s, 0, 0, 0);
        s = __builtin_amdgcn_mfma_f32_16x16x32_bf16(kf, qfl[c], s, 0, 0, 0);
      }
      S[kt] = s;
    }

    // ---- bias + online softmax ----
    float4 ek[4];
    #pragma unroll
    for (int kt = 0; kt < 4; kt++)
      ek[kt] = *(const float4*)&ep[it * 64 + kt * 16 + quad * 4];

    float p[4][4];
    float mx = -3.0e38f;
    #pragma unroll
    for (int kt = 0; kt < 4; kt++) {
      #pragma unroll
      for (int r = 0; r < 4; r++) {
        float d = CLAMP0C((&ek[kt].x)[r] - e2q);
        float sv = S[kt][r] - d;
        p[kt][r] = sv;
        mx = fmaxf(mx, sv);
      }
    }
    mx = fmaxf(mx, __shfl_xor(mx, 16, 64));
    mx = fmaxf(mx, __shfl_xor(mx, 32, 64));
    float mnew = fmaxf(m_i, mx);
    float corr = EXP2(m_i - mnew);
    float ps = 0.f;
    #pragma unroll
    for (int kt = 0; kt < 4; kt++) {
      #pragma unroll
      for (int r = 0; r < 4; r++) {
        float pv = EXP2(p[kt][r] - mnew);
        p[kt][r] = pv;
        ps += pv;
      }
    }
    ps += __shfl_xor(ps, 16, 64);
    ps += __shfl_xor(ps, 32, 64);
    m_i = mnew;
    l_i = l_i * corr + ps;
    #pragma unroll
    for (int dt = 0; dt < 4; dt++) O[dt] *= corr;

    // write P^T bf16 (wave-local scratch, no barrier needed)
    #pragma unroll
    for (int kt = 0; kt < 4; kt++) {
      u32 w0 = pk_bf16(p[kt][0], p[kt][1]);
      u32 w1 = pk_bf16(p[kt][2], p[kt][3]);
      *(uint2*)&Pw[wq][ln][kt * 16 + quad * 4] = make_uint2(w0, w1);
    }

    bfrag pf[2];
    #pragma unroll
    for (int c = 0; c < 2; c++)
      pf[c] = *(const bfrag*)&Pw[wq][ln][c * 32 + quad * 8];

    // ---- O^T += Vt P^T ----
    #pragma unroll
    for (int dt = 0; dt < 4; dt++) {
      ffrag o = O[dt];
      #pragma unroll
      for (int c = 0; c < 2; c++) {
        bfrag vf = *(const bfrag*)(Vh[cur] + frag_off(c, dt * 16 + ln, quad));
        o = __builtin_amdgcn_mfma_f32_16x16x32_bf16(vf, pf[c], o, 0, 0, 0);
      }
      O[dt] = o;
    }
    __syncthreads();   // single barrier: next-tile staging drained (hidden by compute)
  }

  float inv = 1.0f / l_i;
  int row = q0 + wq * 16 + ln;
  #pragma unroll
  for (int dt = 0; dt < 4; dt++) {
    u32 w0 = pk_bf16(O[dt][0] * inv, O[dt][1] * inv);
    u32 w1 = pk_bf16(O[dt][2] * inv, O[dt][3] * inv);
    *(uint2*)&outb[((size_t)(b * N_ + row)) * D_ + h * 64 + dt * 16 + quad * 4] =
        make_uint2(w0, w1);
  }
}

extern "C" void kernel_launch(void* const* d_in, const int* in_sizes, int n_in,
                              void* d_out, int out_size, void* d_ws, size_t ws_size,
                              hipStream_t stream) {
  const float* x      = (const float*)d_in[0];
  const float* elev   = (const float*)d_in[1];
  const float* ln1_g  = (const float*)d_in[2];
  const float* ln1_b  = (const float*)d_in[3];
  const float* qkv_w  = (const float*)d_in[4];
  const float* alpha  = (const float*)d_in[5];
  const float* proj_w = (const float*)d_in[6];
  const float* proj_b = (const float*)d_in[7];
  const float* ln2_g  = (const float*)d_in[8];
  const float* ln2_b  = (const float*)d_in[9];
  const float* fc1_w  = (const float*)d_in[10];
  const float* fc1_b  = (const float*)d_in[11];
  const float* fc2_w  = (const float*)d_in[12];
  const float* fc2_b  = (const float*)d_in[13];
  float* out = (float*)d_out;

  const size_t HBf  = (size_t)B_ * N_ * D_;        // 4,194,304
  const size_t QKE  = (size_t)B_ * N_ * 1024;      // 8,388,608
  const size_t MLPE = (size_t)B_ * N_ * MLP_H_;    // 16,777,216

  char* p = (char*)d_ws;
  u16* abuf = (u16*)p;                     p += HBf * 2;    // LN1 out -> attn out -> LN2 out
  char* region = p;                        p += MLPE * 2;   // qkh+qkl | mlp_hi
  u16* qkh    = (u16*)region;
  u16* qkl    = (u16*)(region + QKE * 2);
  u16* mlp_hi = (u16*)region;
  u16* vth  = (u16*)p;  p += HBf * 2;
  float* xres = (float*)p;                 p += HBf * 4;
  u16* qw_hi = (u16*)p;  p += (size_t)D_ * 3 * D_ * 2;
  u16* qw_lo = (u16*)p;  p += (size_t)D_ * 3 * D_ * 2;
  u16* pw_hi = (u16*)p;  p += (size_t)D_ * D_ * 2;
  u16* f1_hi = (u16*)p;  p += (size_t)D_ * MLP_H_ * 2;
  u16* f2_hi = (u16*)p;  p += (size_t)MLP_H_ * D_ * 2;
  float* e2  = (float*)p; p += (size_t)B_ * N_ * 4;

  const int rows = B_ * N_;   // 8192

  wsplit_all<<<768, 256, 0, stream>>>(qkv_w, proj_w, fc1_w, fc2_w,
                                      qw_hi, qw_lo, pw_hi, f1_hi, f2_hi);
  // LN1 -> abuf (bf16), fused elevation pre-scale
  ln_kernel<<<rows, 256, 0, stream>>>(x, ln1_g, ln1_b, abuf, elev, alpha, e2);
  // fused QKV: Q scale+split, K hi, V^T — one dispatch, 1536 blocks (6/CU)
  qkv_gemm<<<dim3(1536 / 64, rows / 128), 256, 0, stream>>>(
      abuf, qw_hi, qw_lo, qkh, qkl, vth);
  // attention -> abuf (bf16)
  attn_mfma_kernel<<<dim3(N_ / 64, H_, B_), 256, 0, stream>>>(
      qkh, qkl, vth, e2, abuf);
  // xres = x + attn @ proj_w + proj_b : 64x64 tile -> 1024 blocks
  gemm_tpl<64, 64, 2, 2><<<dim3(D_ / 64, rows / 64), 256, 0, stream>>>(
      abuf, pw_hi, proj_b, x, xres, nullptr, rows, D_, D_, 0);
  // LN2 -> abuf (bf16)
  ln_kernel<<<rows, 256, 0, stream>>>(xres, ln2_g, ln2_b, abuf, nullptr, nullptr, nullptr);
  // mlp_hi = bf16(gelu(h2 @ fc1 + b1)) : 64x128 tile -> 2048 blocks (6/CU)
  gemm_tpl<64, 128, 1, 4><<<dim3(MLP_H_ / 128, rows / 64), 256, 0, stream>>>(
      abuf, f1_hi, fc1_b, nullptr, nullptr, mlp_hi, rows, D_, MLP_H_, 1);
  // out = xres + mlp @ fc2 + b2 : 64x64 tile -> 1024 blocks
  gemm_tpl<64, 64, 2, 2><<<dim3(D_ / 64, rows / 64), 256, 0, stream>>>(
      mlp_hi, f2_hi, fc2_b, xres, out, nullptr, rows, MLP_H_, D_, 0);
}

// Round 11
// 346.922 us; speedup vs baseline: 1.0271x; 1.0271x over previous
//
#include <hip/hip_runtime.h>
#include <math.h>

typedef unsigned short u16;
typedef unsigned int u32;

#define B_ 4
#define N_ 2048
#define D_ 512
#define H_ 8
#define HD_ 64
#define MLP_H_ 2048
#define EPS_ 1e-5f
#define C2_ 14.426950408889634f          // 10/ln2
#define QSCALE_ 0.1803368801111204f     // 0.125/ln2
#define EL2_ 0.0014426950408889634f     // 1/(1000*ln2)

#if __has_builtin(__builtin_amdgcn_exp2f)
#define EXP2(x) __builtin_amdgcn_exp2f(x)
#else
#define EXP2(x) exp2f(x)
#endif
#if __has_builtin(__builtin_amdgcn_fmed3f)
#define CLAMP0C(x) __builtin_amdgcn_fmed3f((x), 0.0f, C2_)
#else
#define CLAMP0C(x) fminf(fmaxf((x), 0.0f), C2_)
#endif

// ---------- bf16 helpers ----------
__device__ __forceinline__ u16 bf16_rne(float x) {
  u32 u = __float_as_uint(x);
  u32 r = (u + 0x7FFFu + ((u >> 16) & 1u)) >> 16;
  return (u16)r;
}
#if __has_builtin(__builtin_amdgcn_cvt_pk_bf16_f32)
typedef __bf16 bf2_t __attribute__((ext_vector_type(2)));
__device__ __forceinline__ u32 pk_bf16(float a, float b) {
  bf2_t v = __builtin_amdgcn_cvt_pk_bf16_f32(a, b);
  u32 r; __builtin_memcpy(&r, &v, 4); return r;
}
#else
__device__ __forceinline__ u32 pk_bf16(float a, float b) {
  return (u32)bf16_rne(a) | ((u32)bf16_rne(b) << 16);
}
#endif
__device__ __forceinline__ void bf16_split(float x, u16& h, u16& l) {
  h = bf16_rne(x);
  float hf = __uint_as_float(((u32)h) << 16);
  l = bf16_rne(x - hf);
}

typedef __attribute__((ext_vector_type(8))) short bfrag;
typedef __attribute__((ext_vector_type(4))) float ffrag;

#define LDS_AS(p) ((__attribute__((address_space(3))) void*)(p))
#define GLB_AS(p) ((const __attribute__((address_space(1))) void*)(p))

// ---------------- LayerNorm body (row per block) ----------------
__device__ __forceinline__ void ln_body(
    const float* __restrict__ x, const float* __restrict__ g,
    const float* __restrict__ b, u16* __restrict__ o, int row, int tid)
{
  __shared__ float red[8];
  const float* xr = x + (size_t)row * D_;
  float v0 = xr[tid], v1 = xr[tid + 256];
  float s = v0 + v1;
  #pragma unroll
  for (int off = 32; off > 0; off >>= 1) s += __shfl_xor(s, off, 64);
  if ((tid & 63) == 0) red[tid >> 6] = s;
  __syncthreads();
  float mean = (red[0] + red[1] + red[2] + red[3]) * (1.0f / D_);
  float d0 = v0 - mean, d1 = v1 - mean;
  float vs = d0 * d0 + d1 * d1;
  #pragma unroll
  for (int off = 32; off > 0; off >>= 1) vs += __shfl_xor(vs, off, 64);
  if ((tid & 63) == 0) red[4 + (tid >> 6)] = vs;
  __syncthreads();
  float var = (red[4] + red[5] + red[6] + red[7]) * (1.0f / D_);
  float r = rsqrtf(var + EPS_);
  u16* orow = o + (size_t)row * D_;
  orow[tid]       = bf16_rne(d0 * r * g[tid] + b[tid]);
  orow[tid + 256] = bf16_rne(d1 * r * g[tid + 256] + b[tid + 256]);
}

__global__ __launch_bounds__(256) void ln_kernel(
    const float* __restrict__ x, const float* __restrict__ g,
    const float* __restrict__ b, u16* __restrict__ o)
{
  ln_body(x, g, b, o, blockIdx.x, threadIdx.x);
}

// ---------------- weight split+transpose body ----------------
__device__ __forceinline__ void wsplit_body(
    const float* __restrict__ W, u16* __restrict__ Thi, u16* __restrict__ Tlo,
    int K, int N, int bx, int by, int tid)
{
  __shared__ float tile[64][65];
  int n0 = bx * 64, k0 = by * 64;
  int c = tid & 63, r4 = tid >> 6;
  #pragma unroll
  for (int i = 0; i < 16; i++) {
    int r = r4 + i * 4;
    tile[r][c] = W[(size_t)(k0 + r) * N + n0 + c];
  }
  __syncthreads();
  #pragma unroll
  for (int i = 0; i < 16; i++) {
    int rn = r4 + i * 4;
    float v = tile[c][rn];
    size_t o = (size_t)(n0 + rn) * K + k0 + c;
    if (Tlo) {
      u16 h, l; bf16_split(v, h, l);
      Thi[o] = h; Tlo[o] = l;
    } else {
      Thi[o] = bf16_rne(v);
    }
  }
}

// ---------------- prep: LN1 (blocks 0..8191) + all weight transforms + e2 ------
__global__ __launch_bounds__(256) void prep_kernel(
    const float* __restrict__ x, const float* __restrict__ ln1_g,
    const float* __restrict__ ln1_b, u16* __restrict__ abuf,
    const float* __restrict__ elev, const float* __restrict__ alpha,
    float* __restrict__ e2,
    const float* __restrict__ qkv_w, const float* __restrict__ proj_w,
    const float* __restrict__ fc1_w, const float* __restrict__ fc2_w,
    u16* __restrict__ qw_hi, u16* __restrict__ qw_lo,
    u16* __restrict__ pw_hi, u16* __restrict__ f1_hi, u16* __restrict__ f2_hi)
{
  int blk = blockIdx.x;
  int tid = threadIdx.x;
  if (blk < 8192) {
    if (tid == 0) e2[blk] = elev[blk] * (alpha[0] * EL2_);
    ln_body(x, ln1_g, ln1_b, abuf, blk, tid);
    return;
  }
  int id = blk - 8192;
  if (id < 192) {
    wsplit_body(qkv_w, qw_hi, qw_lo, 512, 1536, id % 24, id / 24, tid);
  } else if (id < 256) {
    int l = id - 192;
    wsplit_body(proj_w, pw_hi, nullptr, 512, 512, l % 8, l / 8, tid);
  } else if (id < 512) {
    int l = id - 256;
    wsplit_body(fc1_w, f1_hi, nullptr, 512, 2048, l % 32, l / 32, tid);
  } else {
    int l = id - 512;
    wsplit_body(fc2_w, f2_hi, nullptr, 2048, 512, l % 8, l / 8, tid);
  }
}

// ---------------- common staging: swizzled 32-k sub-tile ----------------
template<int ROWS>
__device__ __forceinline__ void stage32(const u16* __restrict__ src, int ld,
                                        int r0, int k0, u16* lds, int lane, int wave)
{
  #pragma unroll
  for (int i = 0; i < ROWS / 64; i++) {
    int seg = wave * (ROWS / 64) + i;
    int chunk = seg * 64 + lane;
    int r = chunk >> 2;
    int c = (chunk & 3) ^ ((r >> 1) & 3);
    const u16* g = src + (size_t)(r0 + r) * ld + k0 + c * 8;
    __builtin_amdgcn_global_load_lds(GLB_AS(g), LDS_AS((char*)lds + seg * 1024), 16, 0, 0);
  }
}

__device__ __forceinline__ int swz_off(int R, int quad) {
  return R * 32 + ((quad ^ ((R >> 1) & 3)) * 8);   // u16 units within a 32-k tile
}

// ---------------- fused QKV GEMM: epilogue by column range ----------------
// 128x64 tile, waves 4x1. cols 0-511: Q (scale+split); 512-1023: K (hi); >=1024: V^T.
__global__ __launch_bounds__(256) void qkv_gemm(
    const u16* __restrict__ Ahi,
    const u16* __restrict__ Whi, const u16* __restrict__ Wlo,
    u16* __restrict__ qkh, u16* __restrict__ qkl, u16* __restrict__ vth)
{
  __shared__ __align__(16) u16 As0[128 * 32], As1[128 * 32];
  __shared__ __align__(16) u16 Bh0[64 * 32],  Bh1[64 * 32];
  __shared__ __align__(16) u16 Bl0[64 * 32],  Bl1[64 * 32];

  int tid = threadIdx.x;
  int lane = tid & 63, wave = tid >> 6;
  int ln = lane & 15, quad = lane >> 4;
  int m0 = blockIdx.y * 128, n0 = blockIdx.x * 64;
  bool lo = (n0 < 1024);   // Q/K columns use the 2-term weight path

  ffrag acc[2][4] = {};

  for (int k0 = 0; k0 < D_; k0 += 64) {
    stage32<128>(Ahi, D_, m0, k0,      As0, lane, wave);
    stage32<128>(Ahi, D_, m0, k0 + 32, As1, lane, wave);
    stage32<64>(Whi, D_, n0, k0,      Bh0, lane, wave);
    stage32<64>(Whi, D_, n0, k0 + 32, Bh1, lane, wave);
    if (lo) {
      stage32<64>(Wlo, D_, n0, k0,      Bl0, lane, wave);
      stage32<64>(Wlo, D_, n0, k0 + 32, Bl1, lane, wave);
    }
    __syncthreads();

    #pragma unroll
    for (int hf = 0; hf < 2; hf++) {
      const u16* Asf = hf ? As1 : As0;
      const u16* Bhf = hf ? Bh1 : Bh0;
      const u16* Blf = hf ? Bl1 : Bl0;
      bfrag ah[2], bh[4], bl[4];
      #pragma unroll
      for (int t = 0; t < 2; t++)
        ah[t] = *(const bfrag*)(Asf + swz_off(wave * 32 + t * 16 + ln, quad));
      #pragma unroll
      for (int u = 0; u < 4; u++) {
        int off = swz_off(u * 16 + ln, quad);
        bh[u] = *(const bfrag*)(Bhf + off);
        bl[u] = *(const bfrag*)(Blf + off);
      }
      #pragma unroll
      for (int ti = 0; ti < 2; ti++) {
        #pragma unroll
        for (int tj = 0; tj < 4; tj++) {
          acc[ti][tj] = __builtin_amdgcn_mfma_f32_16x16x32_bf16(ah[ti], bh[tj], acc[ti][tj], 0, 0, 0);
          if (lo)
            acc[ti][tj] = __builtin_amdgcn_mfma_f32_16x16x32_bf16(ah[ti], bl[tj], acc[ti][tj], 0, 0, 0);
        }
      }
    }
    __syncthreads();
  }

  #pragma unroll
  for (int tj = 0; tj < 4; tj++) {
    int col = n0 + tj * 16 + ln;
    #pragma unroll
    for (int ti = 0; ti < 2; ti++) {
      int rw = m0 + wave * 32 + ti * 16 + quad * 4;
      if (col < 512) {          // Q: scale + split
        #pragma unroll
        for (int r = 0; r < 4; r++) {
          float y = acc[ti][tj][r] * QSCALE_;
          u16 hh, ll; bf16_split(y, hh, ll);
          qkh[(size_t)(rw + r) * 1024 + col] = hh;
          qkl[(size_t)(rw + r) * 1024 + col] = ll;
        }
      } else if (col < 1024) {  // K: hi only
        #pragma unroll
        for (int r = 0; r < 4; r++)
          qkh[(size_t)(rw + r) * 1024 + col] = bf16_rne(acc[ti][tj][r]);
      } else {                  // V: write V^T [B,H,HD,N]
        int h = (col - 1024) >> 6, d = (col - 1024) & 63;
        int bb = rw >> 11, n = rw & (N_ - 1);
        u32 w0 = pk_bf16(acc[ti][tj][0], acc[ti][tj][1]);
        u32 w1 = pk_bf16(acc[ti][tj][2], acc[ti][tj][3]);
        size_t dst = ((size_t)((bb * H_ + h) * HD_ + d)) * N_ + n;
        *(uint2*)(vth + dst) = make_uint2(w0, w1);
      }
    }
  }
}

// ---------------- generic GEMM (proj / fc1 / fc2) ----------------
template<int TBM, int TBN, int WR, int WC>
__global__ __launch_bounds__(256) void gemm_tpl(
    const u16* __restrict__ Ahi, const u16* __restrict__ Whi,
    const float* __restrict__ bias, const float* __restrict__ res,
    float* __restrict__ Cf, u16* __restrict__ Ohi,
    int M, int K, int N, int act)
{
  constexpr int MF = TBM / (WR * 16);
  constexpr int NF = TBN / (WC * 16);
  constexpr int AT = TBM * 32;
  constexpr int BT = TBN * 32;
  __shared__ __align__(16) u16 smem[2 * AT + 2 * BT];
  u16* As0 = smem;          u16* As1 = smem + AT;
  u16* Bh0 = smem + 2 * AT; u16* Bh1 = smem + 2 * AT + BT;

  int tid = threadIdx.x;
  int lane = tid & 63, wave = tid >> 6;
  int wr = wave / WC, wc = wave % WC;
  int ln = lane & 15, quad = lane >> 4;
  int m0 = blockIdx.y * TBM, n0 = blockIdx.x * TBN;

  ffrag acc[MF][NF] = {};

  for (int k0 = 0; k0 < K; k0 += 64) {
    stage32<TBM>(Ahi, K, m0, k0,      As0, lane, wave);
    stage32<TBM>(Ahi, K, m0, k0 + 32, As1, lane, wave);
    stage32<TBN>(Whi, K, n0, k0,      Bh0, lane, wave);
    stage32<TBN>(Whi, K, n0, k0 + 32, Bh1, lane, wave);
    __syncthreads();

    #pragma unroll
    for (int hf = 0; hf < 2; hf++) {
      const u16* Asf = hf ? As1 : As0;
      const u16* Bhf = hf ? Bh1 : Bh0;
      bfrag ah[MF], bh[NF];
      #pragma unroll
      for (int t = 0; t < MF; t++)
        ah[t] = *(const bfrag*)(Asf + swz_off(wr * (TBM / WR) + t * 16 + ln, quad));
      #pragma unroll
      for (int u = 0; u < NF; u++)
        bh[u] = *(const bfrag*)(Bhf + swz_off(wc * (TBN / WC) + u * 16 + ln, quad));
      #pragma unroll
      for (int ti = 0; ti < MF; ti++)
        #pragma unroll
        for (int tj = 0; tj < NF; tj++)
          acc[ti][tj] = __builtin_amdgcn_mfma_f32_16x16x32_bf16(ah[ti], bh[tj], acc[ti][tj], 0, 0, 0);
    }
    __syncthreads();
  }

  #pragma unroll
  for (int tj = 0; tj < NF; tj++) {
    int col = n0 + wc * (TBN / WC) + tj * 16 + ln;
    float bv = bias ? bias[col] : 0.f;
    #pragma unroll
    for (int ti = 0; ti < MF; ti++) {
      int rw = m0 + wr * (TBM / WR) + ti * 16 + quad * 4;
      #pragma unroll
      for (int r = 0; r < 4; r++) {
        float y = acc[ti][tj][r] + bv;
        if (act) y = 0.5f * y * (1.f + erff(y * 0.70710678118654752f));
        if (res) y += res[(size_t)(rw + r) * N + col];
        if (Cf) Cf[(size_t)(rw + r) * N + col] = y;
        if (Ohi) Ohi[(size_t)(rw + r) * N + col] = bf16_rne(y);
      }
    }
  }
}

// ---------------- MFMA flash attention (single-buffered, R9 structure) ----------
__device__ __forceinline__ void stage_tile64(const u16* __restrict__ gbase, size_t rstride,
                                             u16* lds, int wave, int lane)
{
  #pragma unroll
  for (int i = 0; i < 2; i++) {
    int seg = wave * 2 + i;
    int chunk = seg * 64 + lane;            // phys chunk 0..511
    int ch = chunk >> 8;                    // 32-elem half
    int pc = chunk & 255;
    int r = pc >> 2;
    int q = (pc & 3) ^ ((r >> 1) & 3);
    const u16* g = gbase + (size_t)r * rstride + ch * 32 + q * 8;
    __builtin_amdgcn_global_load_lds(GLB_AS(g), LDS_AS((char*)lds + seg * 1024), 16, 0, 0);
  }
}

__device__ __forceinline__ int frag_off(int c, int R, int quad) {
  return c * 2048 + R * 32 + ((quad ^ ((R >> 1) & 3)) * 8);   // u16 units
}

__global__ __launch_bounds__(256) void attn_mfma_kernel(
    const u16* __restrict__ qkh, const u16* __restrict__ qkl,
    const u16* __restrict__ vth,
    const float* __restrict__ e2, u16* __restrict__ outb)
{
  __shared__ __align__(16) u16 Kh[4096];
  __shared__ __align__(16) u16 Vh[4096];
  __shared__ __align__(16) u16 Pw[4][16][72];

  int b = blockIdx.z, h = blockIdx.y;
  int q0 = blockIdx.x * 64;
  int tid = threadIdx.x;
  int lane = tid & 63, wq = tid >> 6;
  int ln = lane & 15, quad = lane >> 4;

  // ---- stage Q: hi -> Kh, lo -> Vh ----
  const u16* qb_h = qkh + ((size_t)(b * N_ + q0)) * 1024 + h * 64;
  const u16* qb_l = qkl + ((size_t)(b * N_ + q0)) * 1024 + h * 64;
  stage_tile64(qb_h, 1024, Kh, wq, lane);
  stage_tile64(qb_l, 1024, Vh, wq, lane);
  __syncthreads();

  bfrag qfh[2], qfl[2];
  #pragma unroll
  for (int c = 0; c < 2; c++) {
    int off = frag_off(c, wq * 16 + ln, quad);
    qfh[c] = *(const bfrag*)(Kh + off);
    qfl[c] = *(const bfrag*)(Vh + off);
  }
  __syncthreads();

  float e2q = e2[b * N_ + q0 + wq * 16 + ln];
  float m_i = -3.0e38f, l_i = 0.f;
  ffrag O[4] = {};

  const u16* kp = qkh + (size_t)b * N_ * 1024 + 512 + h * 64;
  const u16* vp = vth + (size_t)(b * H_ + h) * HD_ * N_;
  const float* ep = e2 + b * N_;

  for (int k0 = 0; k0 < N_; k0 += 64) {
    stage_tile64(kp, 1024, Kh, wq, lane);
    stage_tile64(vp, N_, Vh, wq, lane);
    kp += (size_t)64 * 1024;
    vp += 64;
    __syncthreads();

    // ---- S^T = K (Qh+Ql)^T ----
    ffrag S[4];
    #pragma unroll
    for (int kt = 0; kt < 4; kt++) {
      ffrag s = {0.f, 0.f, 0.f, 0.f};
      #pragma unroll
      for (int c = 0; c < 2; c++) {
        bfrag kf = *(const bfrag*)(Kh + frag_off(c, kt * 16 + ln, quad));
        s = __builtin_amdgcn_mfma_f32_16x16x32_bf16(kf, qfh[c], s, 0, 0, 0);
        s = __builtin_amdgcn_mfma_f32_16x16x32_bf16(kf, qfl[c], s, 0, 0, 0);
      }
      S[kt] = s;
    }

    // ---- bias + online softmax ----
    float4 ek[4];
    #pragma unroll
    for (int kt = 0; kt < 4; kt++)
      ek[kt] = *(const float4*)&ep[k0 + kt * 16 + quad * 4];

    float p[4][4];
    float mx = -3.0e38f;
    #pragma unroll
    for (int kt = 0; kt < 4; kt++) {
      #pragma unroll
      for (int r = 0; r < 4; r++) {
        float d = CLAMP0C((&ek[kt].x)[r] - e2q);
        float sv = S[kt][r] - d;
        p[kt][r] = sv;
        mx = fmaxf(mx, sv);
      }
    }
    mx = fmaxf(mx, __shfl_xor(mx, 16, 64));
    mx = fmaxf(mx, __shfl_xor(mx, 32, 64));
    float mnew = fmaxf(m_i, mx);
    float corr = EXP2(m_i - mnew);
    float ps = 0.f;
    #pragma unroll
    for (int kt = 0; kt < 4; kt++) {
      #pragma unroll
      for (int r = 0; r < 4; r++) {
        float pv = EXP2(p[kt][r] - mnew);
        p[kt][r] = pv;
        ps += pv;
      }
    }
    ps += __shfl_xor(ps, 16, 64);
    ps += __shfl_xor(ps, 32, 64);
    m_i = mnew;
    l_i = l_i * corr + ps;
    #pragma unroll
    for (int dt = 0; dt < 4; dt++) O[dt] *= corr;

    // write P^T bf16 (wave-local scratch, no barrier needed)
    #pragma unroll
    for (int kt = 0; kt < 4; kt++) {
      u32 w0 = pk_bf16(p[kt][0], p[kt][1]);
      u32 w1 = pk_bf16(p[kt][2], p[kt][3]);
      *(uint2*)&Pw[wq][ln][kt * 16 + quad * 4] = make_uint2(w0, w1);
    }

    bfrag pf[2];
    #pragma unroll
    for (int c = 0; c < 2; c++)
      pf[c] = *(const bfrag*)&Pw[wq][ln][c * 32 + quad * 8];

    // ---- O^T += Vt P^T ----
    #pragma unroll
    for (int dt = 0; dt < 4; dt++) {
      ffrag o = O[dt];
      #pragma unroll
      for (int c = 0; c < 2; c++) {
        bfrag vf = *(const bfrag*)(Vh + frag_off(c, dt * 16 + ln, quad));
        o = __builtin_amdgcn_mfma_f32_16x16x32_bf16(vf, pf[c], o, 0, 0, 0);
      }
      O[dt] = o;
    }
    __syncthreads();
  }

  float inv = 1.0f / l_i;
  int row = q0 + wq * 16 + ln;
  #pragma unroll
  for (int dt = 0; dt < 4; dt++) {
    u32 w0 = pk_bf16(O[dt][0] * inv, O[dt][1] * inv);
    u32 w1 = pk_bf16(O[dt][2] * inv, O[dt][3] * inv);
    *(uint2*)&outb[((size_t)(b * N_ + row)) * D_ + h * 64 + dt * 16 + quad * 4] =
        make_uint2(w0, w1);
  }
}

extern "C" void kernel_launch(void* const* d_in, const int* in_sizes, int n_in,
                              void* d_out, int out_size, void* d_ws, size_t ws_size,
                              hipStream_t stream) {
  const float* x      = (const float*)d_in[0];
  const float* elev   = (const float*)d_in[1];
  const float* ln1_g  = (const float*)d_in[2];
  const float* ln1_b  = (const float*)d_in[3];
  const float* qkv_w  = (const float*)d_in[4];
  const float* alpha  = (const float*)d_in[5];
  const float* proj_w = (const float*)d_in[6];
  const float* proj_b = (const float*)d_in[7];
  const float* ln2_g  = (const float*)d_in[8];
  const float* ln2_b  = (const float*)d_in[9];
  const float* fc1_w  = (const float*)d_in[10];
  const float* fc1_b  = (const float*)d_in[11];
  const float* fc2_w  = (const float*)d_in[12];
  const float* fc2_b  = (const float*)d_in[13];
  float* out = (float*)d_out;

  const size_t HBf  = (size_t)B_ * N_ * D_;        // 4,194,304
  const size_t QKE  = (size_t)B_ * N_ * 1024;      // 8,388,608
  const size_t MLPE = (size_t)B_ * N_ * MLP_H_;    // 16,777,216

  char* p = (char*)d_ws;
  u16* abuf = (u16*)p;                     p += HBf * 2;    // LN1 out -> attn out -> LN2 out
  char* region = p;                        p += MLPE * 2;   // qkh+qkl | mlp_hi
  u16* qkh    = (u16*)region;
  u16* qkl    = (u16*)(region + QKE * 2);
  u16* mlp_hi = (u16*)region;
  u16* vth  = (u16*)p;  p += HBf * 2;
  float* xres = (float*)p;                 p += HBf * 4;
  u16* qw_hi = (u16*)p;  p += (size_t)D_ * 3 * D_ * 2;
  u16* qw_lo = (u16*)p;  p += (size_t)D_ * 3 * D_ * 2;
  u16* pw_hi = (u16*)p;  p += (size_t)D_ * D_ * 2;
  u16* f1_hi = (u16*)p;  p += (size_t)D_ * MLP_H_ * 2;
  u16* f2_hi = (u16*)p;  p += (size_t)MLP_H_ * D_ * 2;
  float* e2  = (float*)p; p += (size_t)B_ * N_ * 4;

  const int rows = B_ * N_;   // 8192

  // prep: LN1 + e2 + all 4 weight transforms, one launch (8960 blocks)
  prep_kernel<<<rows + 768, 256, 0, stream>>>(
      x, ln1_g, ln1_b, abuf, elev, alpha, e2,
      qkv_w, proj_w, fc1_w, fc2_w, qw_hi, qw_lo, pw_hi, f1_hi, f2_hi);
  // fused QKV: Q scale+split, K hi, V^T — 1536 blocks (6/CU)
  qkv_gemm<<<dim3(1536 / 64, rows / 128), 256, 0, stream>>>(
      abuf, qw_hi, qw_lo, qkh, qkl, vth);
  // attention -> abuf (bf16)
  attn_mfma_kernel<<<dim3(N_ / 64, H_, B_), 256, 0, stream>>>(
      qkh, qkl, vth, e2, abuf);
  // xres = x + attn @ proj_w + proj_b : 64x64 tile -> 1024 blocks
  gemm_tpl<64, 64, 2, 2><<<dim3(D_ / 64, rows / 64), 256, 0, stream>>>(
      abuf, pw_hi, proj_b, x, xres, nullptr, rows, D_, D_, 0);
  // LN2 -> abuf (bf16)
  ln_kernel<<<rows, 256, 0, stream>>>(xres, ln2_g, ln2_b, abuf);
  // mlp_hi = bf16(gelu(h2 @ fc1 + b1)) : 64x128 tile -> 2048 blocks (6/CU)
  gemm_tpl<64, 128, 1, 4><<<dim3(MLP_H_ / 128, rows / 64), 256, 0, stream>>>(
      abuf, f1_hi, fc1_b, nullptr, nullptr, mlp_hi, rows, D_, MLP_H_, 1);
  // out = xres + mlp @ fc2 + b2 : 64x64 tile -> 1024 blocks
  gemm_tpl<64, 64, 2, 2><<<dim3(D_ / 64, rows / 64), 256, 0, stream>>>(
      mlp_hi, f2_hi, fc2_b, xres, out, nullptr, rows, MLP_H_, D_, 0);
}